// Round 1
// baseline (15973.740 us; speedup 1.0000x reference)
//
#include <hip/hip_runtime.h>

// Problem constants (derived defensively from in_sizes in kernel_launch).
#define HDIM 32

// tanh via native v_exp_f32 (computes 2^x) + v_rcp_f32.
// tanh(x) = 1 - 2/(exp(2x)+1) = 1 - 2*rcp(exp2(2*log2(e)*x)+1)
// Saturates correctly for large |x| (exp2->inf -> rcp->0 -> 1; exp2->0 -> -1).
__device__ __forceinline__ float fast_tanh(float x) {
    float e = exp2f(x * 2.8853900817779268f);   // 2*log2(e)
    return 1.0f - 2.0f * __builtin_amdgcn_rcpf(e + 1.0f);
}

// One thread per (n,r) sequence. hid[] lives in VGPRs; W_hh/W_ih/b are
// wave-uniform -> compiler emits s_load + v_fmac with SGPR operand.
// Consumes h[seq][len-1], h[seq][len-2], ..., h[seq][0] (the reversed
// valid prefix), exactly matching the reference's flip+mask scan.
__global__ __launch_bounds__(256) void rnn_kernel(
    const float* __restrict__ h, const int* __restrict__ l,
    const float* __restrict__ W_ih, const float* __restrict__ W_hh,
    const float* __restrict__ b_ih, const float* __restrict__ b_hh,
    float* __restrict__ emb, int nseq, int tmax)
{
    int seq = blockIdx.x * blockDim.x + threadIdx.x;
    if (seq >= nseq) return;
    int len = l[seq];                    // in [0, tmax]
    const float* hp = h + (size_t)seq * tmax;

    float hid[HDIM];
    #pragma unroll
    for (int i = 0; i < HDIM; ++i) hid[i] = 0.0f;

    for (int t = len - 1; t >= 0; --t) {
        float x = hp[t];
        float nh[HDIM];
        #pragma unroll
        for (int i = 0; i < HDIM; ++i)
            nh[i] = fmaf(x, W_ih[i], b_ih[i] + b_hh[i]);  // uniform scalars, hoisted
        #pragma unroll
        for (int j = 0; j < HDIM; ++j) {
            float hj = hid[j];
            #pragma unroll
            for (int i = 0; i < HDIM; ++i)
                nh[i] = fmaf(W_hh[i * HDIM + j], hj, nh[i]);  // s_load + v_fmac
        }
        #pragma unroll
        for (int i = 0; i < HDIM; ++i) hid[i] = fast_tanh(nh[i]);
    }

    float* ep = emb + (size_t)seq * HDIM;
    #pragma unroll
    for (int i = 0; i < HDIM; ++i) ep[i] = hid[i];
}

// One thread per batch row n: feat = emb[n*R*H .. +R*H) (contiguous since
// seq = n*R + r and feat = emb.reshape(N, R*H)).
// z1 = relu(feat@W1+b1); z2 = relu(z1@W2+b2); out = z2@W3+b3.
__global__ __launch_bounds__(256) void mlp_kernel(
    const float* __restrict__ emb,
    const float* __restrict__ W1, const float* __restrict__ b1,
    const float* __restrict__ W2, const float* __restrict__ b2,
    const float* __restrict__ W3, const float* __restrict__ b3,
    float* __restrict__ out, int n, int featdim, int rout)
{
    int i = blockIdx.x * blockDim.x + threadIdx.x;
    if (i >= n) return;
    const float* f = emb + (size_t)i * featdim;

    float z1[32];
    #pragma unroll
    for (int c = 0; c < 32; ++c) z1[c] = b1[c];
    for (int k = 0; k < featdim; k += 4) {       // k uniform -> W1 scalar loads
        float4 fv = *(const float4*)(f + k);
        #pragma unroll
        for (int c = 0; c < 32; ++c) {
            z1[c] = fmaf(fv.x, W1[(k + 0) * 32 + c], z1[c]);
            z1[c] = fmaf(fv.y, W1[(k + 1) * 32 + c], z1[c]);
            z1[c] = fmaf(fv.z, W1[(k + 2) * 32 + c], z1[c]);
            z1[c] = fmaf(fv.w, W1[(k + 3) * 32 + c], z1[c]);
        }
    }
    #pragma unroll
    for (int c = 0; c < 32; ++c) z1[c] = fmaxf(z1[c], 0.0f);

    float z2[32];
    #pragma unroll
    for (int c = 0; c < 32; ++c) z2[c] = b2[c];
    #pragma unroll
    for (int j = 0; j < 32; ++j) {
        float zj = z1[j];
        #pragma unroll
        for (int c = 0; c < 32; ++c)
            z2[c] = fmaf(zj, W2[j * 32 + c], z2[c]);
    }
    #pragma unroll
    for (int c = 0; c < 32; ++c) z2[c] = fmaxf(z2[c], 0.0f);

    float lo[8];
    for (int c = 0; c < rout; ++c) lo[c] = b3[c];
    #pragma unroll
    for (int j = 0; j < 32; ++j) {
        float zj = z2[j];
        for (int c = 0; c < rout; ++c)
            lo[c] = fmaf(zj, W3[j * rout + c], lo[c]);
    }
    for (int c = 0; c < rout; ++c) out[(size_t)i * rout + c] = lo[c];
}

extern "C" void kernel_launch(void* const* d_in, const int* in_sizes, int n_in,
                              void* d_out, int out_size, void* d_ws, size_t ws_size,
                              hipStream_t stream) {
    const float* h    = (const float*)d_in[0];
    const int*   l    = (const int*)d_in[1];
    const float* W_ih = (const float*)d_in[2];
    const float* W_hh = (const float*)d_in[3];
    const float* b_ih = (const float*)d_in[4];
    const float* b_hh = (const float*)d_in[5];
    const float* W1   = (const float*)d_in[6];
    const float* b1   = (const float*)d_in[7];
    const float* W2   = (const float*)d_in[8];
    const float* b2   = (const float*)d_in[9];
    const float* W3   = (const float*)d_in[10];
    const float* b3   = (const float*)d_in[11];
    float* out = (float*)d_out;
    float* emb = (float*)d_ws;                  // (nseq, H) = 131072*32*4B = 16 MB

    const int nseq = in_sizes[1];               // N*R = 131072
    const int tmax = in_sizes[0] / nseq;        // 256
    const int rout = in_sizes[10] / 32;         // W3 is (32, R) -> R = 4
    const int n    = nseq / rout;               // 32768
    const int featdim = rout * HDIM;            // 128

    rnn_kernel<<<(nseq + 255) / 256, 256, 0, stream>>>(
        h, l, W_ih, W_hh, b_ih, b_hh, emb, nseq, tmax);
    mlp_kernel<<<(n + 255) / 256, 256, 0, stream>>>(
        emb, W1, b1, W2, b2, W3, b3, out, n, featdim, rout);
}

// Round 2
// 1180.065 us; speedup vs baseline: 13.5363x; 13.5363x over previous
//
#include <hip/hip_runtime.h>

#define HDIM 32

// tanh via native v_exp_f32 (2^x) + v_rcp_f32; saturates correctly at +-inf.
__device__ __forceinline__ float fast_tanh(float x) {
    float e = exp2f(x * 2.8853900817779268f);   // 2*log2(e)
    return 1.0f - 2.0f * __builtin_amdgcn_rcpf(e + 1.0f);
}

// Lane-transposed RNN: wave = 2 sequences x 32 hidden units.
// lane = half*32 + i ; lane persistently holds W_hh row i (32 VGPRs).
// Per step the 32-float hidden vector round-trips through a per-wave LDS
// slot: 1 ds_write_b32 + 8 broadcast ds_read_b128. Wave-synchronous (no
// __syncthreads -- trip counts diverge per wave); DS ops are in-order per
// wave, fences stop compiler reordering.
__global__ __launch_bounds__(256) void rnn_kernel(
    const float* __restrict__ h, const int* __restrict__ l,
    const float* __restrict__ W_ih, const float* __restrict__ W_hh,
    const float* __restrict__ b_ih, const float* __restrict__ b_hh,
    float* __restrict__ emb, int nseq, int tmax)
{
    const int lane = threadIdx.x & 63;
    const int wv   = threadIdx.x >> 6;            // wave in block: 0..3
    const int half = lane >> 5;                   // 0/1: which sequence
    const int i    = lane & 31;                   // hidden index
    const int seq0 = (blockIdx.x * 4 + wv) * 2 + half;
    const bool live = (seq0 < nseq);
    const int seq  = live ? seq0 : (nseq - 1);

    // Persistent per-lane weight row W_hh[i][0..31] (row-major, i*32+j).
    float wrow[HDIM];
    #pragma unroll
    for (int j = 0; j < HDIM; j += 4) {
        const float4 w4 = *(const float4*)(W_hh + i * HDIM + j);
        wrow[j] = w4.x; wrow[j + 1] = w4.y; wrow[j + 2] = w4.z; wrow[j + 3] = w4.w;
    }
    const float wih  = W_ih[i];
    const float bias = b_ih[i] + b_hh[i];

    int len = live ? l[seq] : 0;
    const float* xp = h + (size_t)seq * tmax;

    __shared__ __align__(16) float hbuf[4][2][HDIM];   // [wave][half][hid]
    float hid = 0.0f;
    hbuf[wv][half][i] = 0.0f;
    __builtin_amdgcn_fence(__ATOMIC_ACQ_REL, "wavefront");

    // trip count = max(len of the two halves); uniform across the wave
    const int other  = __shfl_xor(len, 32);
    const int maxlen = len > other ? len : other;

    // reversed valid prefix: step s consumes x = h[seq][len-1-s]
    float x = (len > 0) ? xp[len - 1] : 0.0f;
    const float* hv = &hbuf[wv][half][0];

    for (int s = 0; s < maxlen; ++s) {
        const bool valid = (s < len);
        // prefetch next step's x so its latency hides under the fmac chain
        float xn = 0.0f;
        if (s + 1 < len) xn = xp[len - 2 - s];

        float acc = bias;
        #pragma unroll
        for (int j = 0; j < HDIM; j += 4) {
            const float4 h4 = *(const float4*)(hv + j);   // ds_read_b128, broadcast
            acc = fmaf(wrow[j],     h4.x, acc);
            acc = fmaf(wrow[j + 1], h4.y, acc);
            acc = fmaf(wrow[j + 2], h4.z, acc);
            acc = fmaf(wrow[j + 3], h4.w, acc);
        }
        acc = fmaf(x, wih, acc);
        const float nh = fast_tanh(acc);
        hid = valid ? nh : hid;       // hold hidden past sequence end

        hbuf[wv][half][i] = hid;
        // order: write(s) must be visible to reads(s+1); DS is in-order per
        // wave, fence blocks compiler motion + emits the lgkmcnt wait.
        __builtin_amdgcn_fence(__ATOMIC_ACQ_REL, "wavefront");
        x = xn;
    }

    if (live) emb[(size_t)seq * HDIM + i] = hid;   // wave writes 256B contiguous
}

// One thread per batch row n: feat = emb[n*R*H .. +R*H) contiguous.
__global__ __launch_bounds__(256) void mlp_kernel(
    const float* __restrict__ emb,
    const float* __restrict__ W1, const float* __restrict__ b1,
    const float* __restrict__ W2, const float* __restrict__ b2,
    const float* __restrict__ W3, const float* __restrict__ b3,
    float* __restrict__ out, int n, int featdim, int rout)
{
    int i = blockIdx.x * blockDim.x + threadIdx.x;
    if (i >= n) return;
    const float* f = emb + (size_t)i * featdim;

    float z1[32];
    #pragma unroll
    for (int c = 0; c < 32; ++c) z1[c] = b1[c];
    for (int k = 0; k < featdim; k += 4) {
        float4 fv = *(const float4*)(f + k);
        #pragma unroll
        for (int c = 0; c < 32; ++c) {
            z1[c] = fmaf(fv.x, W1[(k + 0) * 32 + c], z1[c]);
            z1[c] = fmaf(fv.y, W1[(k + 1) * 32 + c], z1[c]);
            z1[c] = fmaf(fv.z, W1[(k + 2) * 32 + c], z1[c]);
            z1[c] = fmaf(fv.w, W1[(k + 3) * 32 + c], z1[c]);
        }
    }
    #pragma unroll
    for (int c = 0; c < 32; ++c) z1[c] = fmaxf(z1[c], 0.0f);

    float z2[32];
    #pragma unroll
    for (int c = 0; c < 32; ++c) z2[c] = b2[c];
    #pragma unroll
    for (int j = 0; j < 32; ++j) {
        float zj = z1[j];
        #pragma unroll
        for (int c = 0; c < 32; ++c)
            z2[c] = fmaf(zj, W2[j * 32 + c], z2[c]);
    }
    #pragma unroll
    for (int c = 0; c < 32; ++c) z2[c] = fmaxf(z2[c], 0.0f);

    float lo[8];
    for (int c = 0; c < rout; ++c) lo[c] = b3[c];
    #pragma unroll
    for (int j = 0; j < 32; ++j) {
        float zj = z2[j];
        for (int c = 0; c < rout; ++c)
            lo[c] = fmaf(zj, W3[j * rout + c], lo[c]);
    }
    for (int c = 0; c < rout; ++c) out[(size_t)i * rout + c] = lo[c];
}

extern "C" void kernel_launch(void* const* d_in, const int* in_sizes, int n_in,
                              void* d_out, int out_size, void* d_ws, size_t ws_size,
                              hipStream_t stream) {
    const float* h    = (const float*)d_in[0];
    const int*   l    = (const int*)d_in[1];
    const float* W_ih = (const float*)d_in[2];
    const float* W_hh = (const float*)d_in[3];
    const float* b_ih = (const float*)d_in[4];
    const float* b_hh = (const float*)d_in[5];
    const float* W1   = (const float*)d_in[6];
    const float* b1   = (const float*)d_in[7];
    const float* W2   = (const float*)d_in[8];
    const float* b2   = (const float*)d_in[9];
    const float* W3   = (const float*)d_in[10];
    const float* b3   = (const float*)d_in[11];
    float* out = (float*)d_out;
    float* emb = (float*)d_ws;                  // (nseq, H) fp32 = 16 MB

    const int nseq = in_sizes[1];               // N*R = 131072
    const int tmax = in_sizes[0] / nseq;        // 256
    const int rout = in_sizes[10] / 32;         // W3 is (32, R) -> R = 4
    const int n    = nseq / rout;               // 32768
    const int featdim = rout * HDIM;            // 128

    // 2 seqs per wave, 4 waves per block -> 8 seqs per block
    const int nblk = (nseq + 7) / 8;
    rnn_kernel<<<nblk, 256, 0, stream>>>(
        h, l, W_ih, W_hh, b_ih, b_hh, emb, nseq, tmax);
    mlp_kernel<<<(n + 255) / 256, 256, 0, stream>>>(
        emb, W1, b1, W2, b2, W3, b3, out, n, featdim, rout);
}